// Round 11
// baseline (183.569 us; speedup 1.0000x reference)
//
#include <hip/hip_runtime.h>

#define NN   8192
#define FEAT 192
#define HID  256
#define NCLS 1000
#define KNN  9
#define NPP  512          // nodes per image (8192 / 16)
#define NIMG 16
#define KD   192          // dist K (plain bf16)
#define KL0  384          // layer-0 K ([agg|x])
#define NCB  32           // dist col-blocks per row (256 cols per block)

typedef unsigned short ushort_t;
typedef unsigned int uint_t;
typedef __attribute__((ext_vector_type(8))) __bf16 bf16x8;
typedef __attribute__((ext_vector_type(4))) float f32x4;

#define ASYNC16(gptr, lptr)                                                  \
  __builtin_amdgcn_global_load_lds(                                          \
      (const __attribute__((address_space(1))) void*)(gptr),                 \
      (__attribute__((address_space(3))) void*)(lptr), 16, 0, 0)

#define MFMA(a, b, c) __builtin_amdgcn_mfma_f32_16x16x32_bf16((a), (b), (c), 0, 0, 0)

// ---------------------------------------------------------------------------
__device__ __forceinline__ ushort_t f2bf_rne(float f) {
  unsigned u = __float_as_uint(f);
  u += 0x7FFF + ((u >> 16) & 1);          // round-to-nearest-even
  return (ushort_t)(u >> 16);
}
__device__ __forceinline__ float bf2f(ushort_t u) {
  return __uint_as_float((unsigned)u << 16);
}

// sortable-uint transform of float dist, top 19 bits kept, col13 in low bits.
__device__ __forceinline__ uint_t packkey(float f, int col) {
  uint_t b = __float_as_uint(f);
  uint_t m = (uint_t)((int)b >> 31) | 0x80000000u;
  uint_t u = b ^ m;
  return (u & 0xFFFFE000u) | (uint_t)col;
}

__device__ __forceinline__ uint_t umed3(uint_t a, uint_t b, uint_t c) {
  uint_t d;
  asm("v_med3_u32 %0, %1, %2, %3" : "=v"(d) : "v"(a), "v"(b), "v"(c));
  return d;
}

// keep-9-smallest insert into ascending-sorted tk[] via med3 (9 ops).
__device__ __forceinline__ void bubble9(uint_t (&tk)[KNN], uint_t k) {
#pragma unroll
  for (int p = KNN - 1; p > 0; --p) tk[p] = umed3(tk[p - 1], tk[p], k);
  tk[0] = min(tk[0], k);
}

// ---------------------------------------------------------------------------
// prep: row norms + bf16 cast of x | weight transpose-cast | zero out
__global__ __launch_bounds__(256) void k_prep(
    const float* __restrict__ x, float* __restrict__ sq,
    ushort_t* __restrict__ xs,
    const float* __restrict__ w_l0, const float* __restrict__ w_r0,
    const float* __restrict__ w_l1, const float* __restrict__ w_r1,
    const float* __restrict__ w_l2, const float* __restrict__ w_r2,
    ushort_t* __restrict__ WT0, ushort_t* __restrict__ WT1,
    ushort_t* __restrict__ WT2, float* __restrict__ out) {
  const int blk = blockIdx.x, t = threadIdx.x;
  if (blk < 2048) {                        // norms + cast, wave per row
    int wid  = (blk * 256 + t) >> 6;
    int lane = t & 63;
    const float* row = x + (size_t)wid * FEAT;
    ushort_t* xr = xs + (size_t)wid * KD;
    float s = 0.f;
#pragma unroll
    for (int f0 = 0; f0 < FEAT; f0 += 64) {
      int f = f0 + lane;
      float v = row[f];
      s += v * v;
      xr[f] = f2bf_rne(v);
    }
#pragma unroll
    for (int off = 32; off > 0; off >>= 1) s += __shfl_down(s, off);
    if (lane == 0) sq[wid] = s;
    return;
  }
  int i = (blk - 2048) * 256 + t;          // 0 .. 753663
  if (i < NIMG * NCLS) out[i] = 0.f;
  if (i < 98304) {                         // WT0: 256 x 384
    int n = i / 384, k = i - n * 384;
    float v = (k < 192) ? w_l0[k * 256 + n] : w_r0[(k - 192) * 256 + n];
    WT0[i] = f2bf_rne(v);
  } else if (i < 98304 + 131072) {         // WT1: 256 x 512
    int j = i - 98304;
    int n = j / 512, k = j - n * 512;
    float v = (k < 256) ? w_l1[k * 256 + n] : w_r1[(k - 256) * 256 + n];
    WT1[j] = f2bf_rne(v);
  } else {                                 // WT2: 1024 x 512 (rows>=1000: 0)
    int j = i - (98304 + 131072);
    int n = j / 512, k = j - n * 512;
    float v = 0.f;
    if (n < NCLS)
      v = (k < 256) ? w_l2[k * NCLS + n] : w_r2[(k - 256) * NCLS + n];
    WT2[j] = f2bf_rne(v);
  }
}

// ---------------------------------------------------------------------------
// MFMA distance + top-9. R11: each block covers 128 rows x 256 cols via two
// sequential 128-col tiles folding into ONE per-thread tk — halves cand
// volume and downstream merge work. Grid 32 x 64.
__global__ __launch_bounds__(256, 4) void k_dist_topk(
    const ushort_t* __restrict__ xs, const float* __restrict__ sq,
    uint_t* __restrict__ cand) {
  __shared__ __align__(16) char smem[24576];
  ushort_t* As = (ushort_t*)smem;            // [128][32] (granule-swizzled)
  ushort_t* Bs = (ushort_t*)(smem + 8192);
  uint_t*   Ms = (uint_t*)(smem + 19456);    // [128][10] merge buf

  const int t    = threadIdx.x;
  const int lane = t & 63;
  const int w    = t >> 6;
  const int l15  = lane & 15, lq = lane >> 4;
  const int rowStart = blockIdx.y * 128;
  const int colBase  = blockIdx.x * 256;
  const int mrow = (w >> 1) * 64;
  const int ncol = (w & 1) * 64;

  const int m0 = w * 128 + lane;
  const int r0 = m0 >> 2, r1 = r0 + 16;
  const int g0 = m0 & 3;
  const int gs0 = g0 ^ (r0 & 3);
  const int gs1 = g0 ^ (r1 & 3);
  const ushort_t* gA0 = xs + (size_t)(rowStart + r0) * KD + gs0 * 8;
  const ushort_t* gA1 = xs + (size_t)(rowStart + r1) * KD + gs1 * 8;
  ushort_t* lA = As + w * 1024;
  ushort_t* lB = Bs + w * 1024;

  const int pg = (lq ^ (l15 & 3)) * 8;
  int aoff[4], boff[4];
#pragma unroll
  for (int ti = 0; ti < 4; ++ti) aoff[ti] = (mrow + ti * 16 + l15) * 32 + pg;
#pragma unroll
  for (int tj = 0; tj < 4; ++tj) boff[tj] = (ncol + tj * 16 + l15) * 32 + pg;

  uint_t tk[KNN];
#pragma unroll
  for (int n = 0; n < KNN; ++n) tk[n] = 0xFFFFFFFFu;

  uint_t* Ew = (uint_t*)smem + w * (64 * 19);

#pragma unroll 1
  for (int ct = 0; ct < 2; ++ct) {
    const int colStart = colBase + ct * 128;
    const ushort_t* gB0 = xs + (size_t)(colStart + r0) * KD + gs0 * 8;
    const ushort_t* gB1 = xs + (size_t)(colStart + r1) * KD + gs1 * 8;

    f32x4 c00 = {}, c01 = {}, c02 = {}, c03 = {};
    f32x4 c10 = {}, c11 = {}, c12 = {}, c13 = {};
    f32x4 c20 = {}, c21 = {}, c22 = {}, c23 = {};
    f32x4 c30 = {}, c31 = {}, c32 = {}, c33 = {};

#pragma unroll 1
    for (int kt = 0; kt < 6; ++kt) {
      const int k0 = kt * 32;
      ASYNC16(gA0 + k0, lA);
      ASYNC16(gA1 + k0, lA + 512);
      ASYNC16(gB0 + k0, lB);
      ASYNC16(gB1 + k0, lB + 512);
      __syncthreads();
      bf16x8 a0 = *(const bf16x8*)(As + aoff[0]);
      bf16x8 a1 = *(const bf16x8*)(As + aoff[1]);
      bf16x8 a2 = *(const bf16x8*)(As + aoff[2]);
      bf16x8 a3 = *(const bf16x8*)(As + aoff[3]);
      bf16x8 b0 = *(const bf16x8*)(Bs + boff[0]);
      bf16x8 b1 = *(const bf16x8*)(Bs + boff[1]);
      bf16x8 b2 = *(const bf16x8*)(Bs + boff[2]);
      bf16x8 b3 = *(const bf16x8*)(Bs + boff[3]);
      c00 = MFMA(a0, b0, c00); c01 = MFMA(a0, b1, c01);
      c02 = MFMA(a0, b2, c02); c03 = MFMA(a0, b3, c03);
      c10 = MFMA(a1, b0, c10); c11 = MFMA(a1, b1, c11);
      c12 = MFMA(a1, b2, c12); c13 = MFMA(a1, b3, c13);
      c20 = MFMA(a2, b0, c20); c21 = MFMA(a2, b1, c21);
      c22 = MFMA(a2, b2, c22); c23 = MFMA(a2, b3, c23);
      c30 = MFMA(a3, b0, c30); c31 = MFMA(a3, b1, c31);
      c32 = MFMA(a3, b2, c32); c33 = MFMA(a3, b3, c33);
      __syncthreads();
    }

#define EPI_ROW(TI, CV)                                                      \
  do {                                                                       \
    f32x4 v_ = (CV);                                                         \
    Ew[((TI) * 16 + lq * 4 + 0) * 19 + l15] =                                \
        packkey(fmaf(-2.0f, v_.x, sqv), mycol);                              \
    Ew[((TI) * 16 + lq * 4 + 1) * 19 + l15] =                                \
        packkey(fmaf(-2.0f, v_.y, sqv), mycol);                              \
    Ew[((TI) * 16 + lq * 4 + 2) * 19 + l15] =                                \
        packkey(fmaf(-2.0f, v_.z, sqv), mycol);                              \
    Ew[((TI) * 16 + lq * 4 + 3) * 19 + l15] =                                \
        packkey(fmaf(-2.0f, v_.w, sqv), mycol);                              \
  } while (0)

#define EPI_TILE(TJ, C0, C1, C2, C3)                                         \
  do {                                                                       \
    int mycol = colStart + ncol + (TJ) * 16 + l15;                           \
    float sqv = sq[mycol];                                                   \
    EPI_ROW(0, C0); EPI_ROW(1, C1); EPI_ROW(2, C2); EPI_ROW(3, C3);          \
    _Pragma("unroll")                                                        \
    for (int c = 0; c < 16; ++c) bubble9(tk, Ew[lane * 19 + c]);             \
  } while (0)

    EPI_TILE(0, c00, c10, c20, c30);
    EPI_TILE(1, c01, c11, c21, c31);
    EPI_TILE(2, c02, c12, c22, c32);
    EPI_TILE(3, c03, c13, c23, c33);

    __syncthreads();   // Ew (overlaps As/Bs) dead before next ct staging
  }

  // merge the two waves sharing each row half, write 9 keys per 256 cols
  if (w & 1) {
#pragma unroll
    for (int n = 0; n < KNN; ++n) Ms[(mrow + lane) * 10 + n] = tk[n];
  }
  __syncthreads();
  if (!(w & 1)) {
#pragma unroll
    for (int n = 0; n < KNN; ++n) bubble9(tk, Ms[(mrow + lane) * 10 + n]);
    size_t base =
        (((size_t)(rowStart + mrow + lane)) * NCB + blockIdx.x) * KNN;
#pragma unroll
    for (int n = 0; n < KNN; ++n) cand[base + n] = tk[n];
  }
}

// ---------------------------------------------------------------------------
// fused: merge 32x9=288 packed candidates -> 9 neighbor idx -> layer-0 gather.
__global__ __launch_bounds__(256) void k_reduce_gather(
    const uint_t* __restrict__ cand, const float* __restrict__ x,
    int* __restrict__ idx, ushort_t* __restrict__ Ab0) {
  int wid  = (blockIdx.x * 256 + threadIdx.x) >> 6;
  int lane = threadIdx.x & 63;
  if (wid >= NN) return;
  const uint_t* cv = cand + (size_t)wid * (NCB * KNN);
  uint_t tk[KNN];
#pragma unroll
  for (int n = 0; n < KNN; ++n) tk[n] = 0xFFFFFFFFu;
#pragma unroll
  for (int m = 0; m < 4; ++m) bubble9(tk, cv[lane + 64 * m]);
  bubble9(tk, (lane < 32) ? cv[lane + 256] : 0xFFFFFFFFu);

  int nb[KNN];
  for (int r = 0; r < KNN; ++r) {
    uint_t bm = tk[0];
#pragma unroll
    for (int off = 32; off > 0; off >>= 1)
      bm = min(bm, (uint_t)__shfl_xor((unsigned int)bm, off));
    if (tk[0] == bm) {
#pragma unroll
      for (int p = 0; p < KNN - 1; ++p) tk[p] = tk[p + 1];
      tk[KNN - 1] = 0xFFFFFFFFu;
    }
    nb[r] = (int)(bm & 0x1FFFu);
    if (lane == 0) idx[wid * KNN + r] = nb[r];
  }

#pragma unroll
  for (int f0 = 0; f0 < FEAT; f0 += 64) {
    int f = f0 + lane;
    float s = 0.f;
#pragma unroll
    for (int n = 0; n < KNN; ++n) s += x[(size_t)nb[n] * FEAT + f];
    Ab0[(size_t)wid * KL0 + f]        = f2bf_rne(s * (1.0f / KNN));
    Ab0[(size_t)wid * KL0 + FEAT + f] = f2bf_rne(x[(size_t)wid * FEAT + f]);
  }
}

// ---------------------------------------------------------------------------
// layer-1/2 agg build: 16B/lane, 2 rows per wave (32 lanes x 8 cols = 256).
__global__ __launch_bounds__(256) void k_gather_h(
    const ushort_t* __restrict__ hsrc, const int* __restrict__ idx,
    ushort_t* __restrict__ adst) {
  const int t = threadIdx.x;
  const int lane = t & 63, w = t >> 6;
  const int r  = (blockIdx.x * 4 + w) * 2 + (lane >> 5);
  const int cl = (lane & 31) * 8;
  int nb[KNN];
#pragma unroll
  for (int n = 0; n < KNN; ++n) nb[n] = idx[r * KNN + n];
  float s[8] = {};
#pragma unroll
  for (int n = 0; n < KNN; ++n) {
    uint4 v = *(const uint4*)(hsrc + (size_t)nb[n] * 512 + cl);
    s[0] += __uint_as_float(v.x << 16); s[1] += __uint_as_float(v.x & 0xFFFF0000u);
    s[2] += __uint_as_float(v.y << 16); s[3] += __uint_as_float(v.y & 0xFFFF0000u);
    s[4] += __uint_as_float(v.z << 16); s[5] += __uint_as_float(v.z & 0xFFFF0000u);
    s[6] += __uint_as_float(v.w << 16); s[7] += __uint_as_float(v.w & 0xFFFF0000u);
  }
  uint4 o;
  o.x = (uint_t)f2bf_rne(s[0] * (1.0f / KNN)) |
        ((uint_t)f2bf_rne(s[1] * (1.0f / KNN)) << 16);
  o.y = (uint_t)f2bf_rne(s[2] * (1.0f / KNN)) |
        ((uint_t)f2bf_rne(s[3] * (1.0f / KNN)) << 16);
  o.z = (uint_t)f2bf_rne(s[4] * (1.0f / KNN)) |
        ((uint_t)f2bf_rne(s[5] * (1.0f / KNN)) << 16);
  o.w = (uint_t)f2bf_rne(s[6] * (1.0f / KNN)) |
        ((uint_t)f2bf_rne(s[7] * (1.0f / KNN)) << 16);
  *(uint4*)(adst + (size_t)r * 512 + cl) = o;
}

// ---------------------------------------------------------------------------
// bf16 MFMA SAGE layer, BM=64 BN=64, N=256, 512 blocks. BK=64 (2 panels per
// barrier pair — halves syncthreads vs BK=32).
__global__ __launch_bounds__(256) void k_sage64(
    const ushort_t* __restrict__ Ab, const ushort_t* __restrict__ WT,
    const float* __restrict__ bias, ushort_t* __restrict__ hdst, int KT) {
  __shared__ __align__(16) char smem[16384];
  ushort_t* As = (ushort_t*)smem;            // 2 panels [64][32]
  ushort_t* Bs = (ushort_t*)(smem + 8192);
  const int blk = blockIdx.x;
  const int t = threadIdx.x;
  const int lane = t & 63, w = t >> 6;
  const int l15 = lane & 15, lq = lane >> 4;
  const int rowStart = (blk >> 2) * 64, colStart = (blk & 3) * 64;
  const int mrow = (w >> 1) * 32, ncol = (w & 1) * 32;

  const int rA = t >> 2, g = t & 3;
  const int gs = g ^ (rA & 3);
  const ushort_t* gA = Ab + (size_t)(rowStart + rA) * KT + gs * 8;
  const ushort_t* gB = WT + (size_t)(colStart + rA) * KT + gs * 8;
  ushort_t* lA = As + w * 512;
  ushort_t* lB = Bs + w * 512;

  const int pg = (lq ^ (l15 & 3)) * 8;
  const int aoff0 = (mrow + l15) * 32 + pg, aoff1 = (mrow + 16 + l15) * 32 + pg;
  const int boff0 = (ncol + l15) * 32 + pg, boff1 = (ncol + 16 + l15) * 32 + pg;

  f32x4 c00 = {}, c01 = {}, c10 = {}, c11 = {};
  const int nkt = KT >> 6;
#pragma unroll 1
  for (int kt = 0; kt < nkt; ++kt) {
    const int k0 = kt * 64;
    ASYNC16(gA + k0, lA);
    ASYNC16(gA + k0 + 32, lA + 2048);
    ASYNC16(gB + k0, lB);
    ASYNC16(gB + k0 + 32, lB + 2048);
    __syncthreads();
    bf16x8 a0 = *(const bf16x8*)(As + aoff0);
    bf16x8 a1 = *(const bf16x8*)(As + aoff1);
    bf16x8 b0 = *(const bf16x8*)(Bs + boff0);
    bf16x8 b1 = *(const bf16x8*)(Bs + boff1);
    c00 = MFMA(a0, b0, c00); c01 = MFMA(a0, b1, c01);
    c10 = MFMA(a1, b0, c10); c11 = MFMA(a1, b1, c11);
    bf16x8 a0p = *(const bf16x8*)(As + 2048 + aoff0);
    bf16x8 a1p = *(const bf16x8*)(As + 2048 + aoff1);
    bf16x8 b0p = *(const bf16x8*)(Bs + 2048 + boff0);
    bf16x8 b1p = *(const bf16x8*)(Bs + 2048 + boff1);
    c00 = MFMA(a0p, b0p, c00); c01 = MFMA(a0p, b1p, c01);
    c10 = MFMA(a1p, b0p, c10); c11 = MFMA(a1p, b1p, c11);
    __syncthreads();
  }

  const float bv0 = bias[colStart + ncol + l15];
  const float bv1 = bias[colStart + ncol + 16 + l15];
#define S64_ST(TI, TJ, CV, BV)                                               \
  do {                                                                       \
    f32x4 v_ = (CV);                                                         \
    int col_ = colStart + ncol + (TJ) * 16 + l15;                            \
    size_t rb_ = (size_t)(rowStart + mrow + (TI) * 16 + lq * 4);             \
    hdst[(rb_ + 0) * 512 + col_] = f2bf_rne(fmaxf(v_.x + (BV), 0.f));        \
    hdst[(rb_ + 1) * 512 + col_] = f2bf_rne(fmaxf(v_.y + (BV), 0.f));        \
    hdst[(rb_ + 2) * 512 + col_] = f2bf_rne(fmaxf(v_.z + (BV), 0.f));        \
    hdst[(rb_ + 3) * 512 + col_] = f2bf_rne(fmaxf(v_.w + (BV), 0.f));        \
  } while (0)
  S64_ST(0, 0, c00, bv0); S64_ST(0, 1, c01, bv1);
  S64_ST(1, 0, c10, bv0); S64_ST(1, 1, c11, bv1);
}

// ---------------------------------------------------------------------------
// bf16 MFMA layer-2 + fused global mean pool. BM=128 BN=128, N=1024 padded,
// KT=512, BK=64 (2 panels per barrier pair).
__global__ __launch_bounds__(256, 2) void k_sage128_pool(
    const ushort_t* __restrict__ Ab, const ushort_t* __restrict__ WT,
    const float* __restrict__ bias, float* __restrict__ out) {
  __shared__ __align__(16) char smem[32768];
  ushort_t* As = (ushort_t*)smem;            // 2 panels [128][32]
  ushort_t* Bs = (ushort_t*)(smem + 16384);
  __shared__ float Ps[2][128];

  const int t    = threadIdx.x;
  const int lane = t & 63;
  const int w    = t >> 6;
  const int l15  = lane & 15, lq = lane >> 4;
  const int rowStart = blockIdx.y * 128;
  const int colStart = blockIdx.x * 128;
  const int mrow = (w >> 1) * 64;
  const int ncol = (w & 1) * 64;
  const int KT = 512;

  const int rA0 = t >> 2, rA1 = rA0 + 64;
  const int g = t & 3;
  const int gsA0 = g ^ (rA0 & 3), gsA1 = g ^ (rA1 & 3);
  const ushort_t* gA0 = Ab + (size_t)(rowStart + rA0) * KT + gsA0 * 8;
  const ushort_t* gA1 = Ab + (size_t)(rowStart + rA1) * KT + gsA1 * 8;
  const ushort_t* gB0 = WT + (size_t)(colStart + rA0) * KT + gsA0 * 8;
  const ushort_t* gB1 = WT + (size_t)(colStart + rA1) * KT + gsA1 * 8;
  ushort_t* lA0 = As + w * 512;
  ushort_t* lA1 = As + 2048 + w * 512;
  ushort_t* lB0 = Bs + w * 512;
  ushort_t* lB1 = Bs + 2048 + w * 512;

  const int pg = (lq ^ (l15 & 3)) * 8;
  int aoff[4], boff[4];
#pragma unroll
  for (int ti = 0; ti < 4; ++ti) aoff[ti] = (mrow + ti * 16 + l15) * 32 + pg;
#pragma unroll
  for (int tj = 0; tj < 4; ++tj) boff[tj] = (ncol + tj * 16 + l15) * 32 + pg;

  f32x4 c00 = {}, c01 = {}, c02 = {}, c03 = {};
  f32x4 c10 = {}, c11 = {}, c12 = {}, c13 = {};
  f32x4 c20 = {}, c21 = {}, c22 = {}, c23 = {};
  f32x4 c30 = {}, c31 = {}, c32 = {}, c33 = {};

#define POOL_MFMA_PANEL(OFS)                                                 \
  do {                                                                       \
    bf16x8 a0 = *(const bf16x8*)(As + (OFS) + aoff[0]);                      \
    bf16x8 a1 = *(const bf16x8*)(As + (OFS) + aoff[1]);                      \
    bf16x8 a2 = *(const bf16x8*)(As + (OFS) + aoff[2]);                      \
    bf16x8 a3 = *(const bf16x8*)(As + (OFS) + aoff[3]);                      \
    bf16x8 b0v = *(const bf16x8*)(Bs + (OFS) + boff[0]);                     \
    bf16x8 b1v = *(const bf16x8*)(Bs + (OFS) + boff[1]);                     \
    bf16x8 b2v = *(const bf16x8*)(Bs + (OFS) + boff[2]);                     \
    bf16x8 b3v = *(const bf16x8*)(Bs + (OFS) + boff[3]);                     \
    c00 = MFMA(a0, b0v, c00); c01 = MFMA(a0, b1v, c01);                      \
    c02 = MFMA(a0, b2v, c02); c03 = MFMA(a0, b3v, c03);                      \
    c10 = MFMA(a1, b0v, c10); c11 = MFMA(a1, b1v, c11);                      \
    c12 = MFMA(a1, b2v, c12); c13 = MFMA(a1, b3v, c13);                      \
    c20 = MFMA(a2, b0v, c20); c21 = MFMA(a2, b1v, c21);                      \
    c22 = MFMA(a2, b2v, c22); c23 = MFMA(a2, b3v, c23);                      \
    c30 = MFMA(a3, b0v, c30); c31 = MFMA(a3, b1v, c31);                      \
    c32 = MFMA(a3, b2v, c32); c33 = MFMA(a3, b3v, c33);                      \
  } while (0)

#pragma unroll 1
  for (int kt = 0; kt < 8; ++kt) {
    const int k0 = kt * 64;
    ASYNC16(gA0 + k0, lA0);
    ASYNC16(gA1 + k0, lA1);
    ASYNC16(gA0 + k0 + 32, lA0 + 4096);
    ASYNC16(gA1 + k0 + 32, lA1 + 4096);
    ASYNC16(gB0 + k0, lB0);
    ASYNC16(gB1 + k0, lB1);
    ASYNC16(gB0 + k0 + 32, lB0 + 4096);
    ASYNC16(gB1 + k0 + 32, lB1 + 4096);
    __syncthreads();
    POOL_MFMA_PANEL(0);
    POOL_MFMA_PANEL(4096);
    __syncthreads();
  }

#define P_ACC(CV)                                                            \
  (fmaxf((CV).x + bv_, 0.f) + fmaxf((CV).y + bv_, 0.f) +                     \
   fmaxf((CV).z + bv_, 0.f) + fmaxf((CV).w + bv_, 0.f))

#define POOL_COL(TJ, C0, C1, C2, C3)                                         \
  do {                                                                       \
    int col_ = colStart + ncol + (TJ) * 16 + l15;                            \
    float bv_ = (col_ < NCLS) ? bias[col_] : 0.f;                            \
    float s_ = P_ACC(C0) + P_ACC(C1) + P_ACC(C2) + P_ACC(C3);                \
    s_ += __shfl_xor(s_, 16);                                                \
    s_ += __shfl_xor(s_, 32);                                                \
    if (lq == 0) Ps[w >> 1][ncol + (TJ) * 16 + l15] = s_;                    \
  } while (0)

  POOL_COL(0, c00, c10, c20, c30);
  POOL_COL(1, c01, c11, c21, c31);
  POOL_COL(2, c02, c12, c22, c32);
  POOL_COL(3, c03, c13, c23, c33);

  __syncthreads();
  if (t < 128) {
    int col = colStart + t;
    if (col < NCLS) {
      float s = Ps[0][t] + Ps[1][t];
      int img = rowStart / NPP;
      atomicAdd(out + (size_t)img * NCLS + col, s * (1.0f / NPP));
    }
  }
}

// ---------------------------------------------------------------------------
extern "C" void kernel_launch(void* const* d_in, const int* in_sizes, int n_in,
                              void* d_out, int out_size, void* d_ws,
                              size_t ws_size, hipStream_t stream) {
  const float* x    = (const float*)d_in[0];
  const float* w_l0 = (const float*)d_in[1];
  const float* b_l0 = (const float*)d_in[2];
  const float* w_r0 = (const float*)d_in[3];
  const float* w_l1 = (const float*)d_in[4];
  const float* b_l1 = (const float*)d_in[5];
  const float* w_r1 = (const float*)d_in[6];
  const float* w_l2 = (const float*)d_in[7];
  const float* b_l2 = (const float*)d_in[8];
  const float* w_r2 = (const float*)d_in[9];
  float* out = (float*)d_out;

  char* ws = (char*)d_ws;
  // WT lifetime rule (R9 lesson): WTs written by k_prep must live OUTSIDE
  // the cand region; only Ab1/Ab2 (written after k_reduce_gather) overlap it.
  // cand now 8192*288*4 = 9.44 MB: [327680, 9764864).
  // sq [0,32K) | idx [32K,320K) | cand [327680, 9764864) |
  // xs [19202048, 22347776) | Ab0 [22347776, 28639232) |
  // WT0 @28639232 WT1 @28835840 WT2 @29097984..30146560 |
  // Ab1 [327680, 8716288) Ab2 [8716288, 17104896)
  float*    sq   = (float*)(ws);
  int*      idx  = (int*)(ws + 32768);
  uint_t*   cand = (uint_t*)(ws + 327680);
  ushort_t* xs   = (ushort_t*)(ws + 19202048);
  ushort_t* Ab0  = (ushort_t*)(ws + 22347776);
  ushort_t* WT0  = (ushort_t*)(ws + 28639232);
  ushort_t* WT1  = (ushort_t*)(ws + 28835840);
  ushort_t* WT2  = (ushort_t*)(ws + 29097984);
  ushort_t* Ab1  = (ushort_t*)(ws + 327680);
  ushort_t* Ab2  = (ushort_t*)(ws + 8716288);

  k_prep<<<4992, 256, 0, stream>>>(x, sq, xs, w_l0, w_r0, w_l1, w_r1,
                                   w_l2, w_r2, WT0, WT1, WT2, out);
  k_dist_topk<<<dim3(NCB, 64), 256, 0, stream>>>(xs, sq, cand);
  k_reduce_gather<<<2048, 256, 0, stream>>>(cand, x, idx, Ab0);
  k_sage64<<<512, 256, 0, stream>>>(Ab0, WT0, b_l0, Ab1 + 256, KL0);
  k_gather_h<<<1024, 256, 0, stream>>>(Ab1 + 256, idx, Ab1);
  k_sage64<<<512, 256, 0, stream>>>(Ab1, WT1, b_l1, Ab2 + 256, 512);
  k_gather_h<<<1024, 256, 0, stream>>>(Ab2 + 256, idx, Ab2);
  k_sage128_pool<<<dim3(8, 64), 256, 0, stream>>>(Ab2, WT2, b_l2, out);
}

// Round 12
// 181.846 us; speedup vs baseline: 1.0095x; 1.0095x over previous
//
#include <hip/hip_runtime.h>

#define NN   8192
#define FEAT 192
#define HID  256
#define NCLS 1000
#define KNN  9
#define NPP  512          // nodes per image (8192 / 16)
#define NIMG 16
#define KD   192          // dist K (plain bf16)
#define KL0  384          // layer-0 K ([agg|x])
#define NCB  32           // dist col-blocks per row (256 cols per block)
#define FINF 3.402823466e38f

typedef unsigned short ushort_t;
typedef unsigned int uint_t;
typedef __attribute__((ext_vector_type(8))) __bf16 bf16x8;
typedef __attribute__((ext_vector_type(4))) float f32x4;

#define ASYNC16(gptr, lptr)                                                  \
  __builtin_amdgcn_global_load_lds(                                          \
      (const __attribute__((address_space(1))) void*)(gptr),                 \
      (__attribute__((address_space(3))) void*)(lptr), 16, 0, 0)

#define MFMA(a, b, c) __builtin_amdgcn_mfma_f32_16x16x32_bf16((a), (b), (c), 0, 0, 0)

// ---------------------------------------------------------------------------
__device__ __forceinline__ ushort_t f2bf_rne(float f) {
  unsigned u = __float_as_uint(f);
  u += 0x7FFF + ((u >> 16) & 1);          // round-to-nearest-even
  return (ushort_t)(u >> 16);
}
__device__ __forceinline__ float bf2f(ushort_t u) {
  return __uint_as_float((unsigned)u << 16);
}

// f32 sort key: distance value with col stuffed into low 13 mantissa bits
// (single v_and_or_b32). Float order = numeric order; keeps 10 mantissa bits
// of precision (same as the previous sortable-uint packkey). Keys unique per
// row because each col is scanned exactly once.
__device__ __forceinline__ float packf(float v, int col) {
  return __uint_as_float((__float_as_uint(v) & 0xFFFFE000u) | (uint_t)col);
}

__device__ __forceinline__ float fmed3(float a, float b, float c) {
  float d;
  asm("v_med3_f32 %0, %1, %2, %3" : "=v"(d) : "v"(a), "v"(b), "v"(c));
  return d;
}

// keep-9-smallest insert into ascending-sorted float tk[] via med3 (9 ops).
__device__ __forceinline__ void bubble9f(float (&tk)[KNN], float k) {
#pragma unroll
  for (int p = KNN - 1; p > 0; --p) tk[p] = fmed3(tk[p - 1], tk[p], k);
  tk[0] = fminf(tk[0], k);
}

// ---------------------------------------------------------------------------
// prep: row norms + bf16 cast of x | weight transpose-cast | zero out
__global__ __launch_bounds__(256) void k_prep(
    const float* __restrict__ x, float* __restrict__ sq,
    ushort_t* __restrict__ xs,
    const float* __restrict__ w_l0, const float* __restrict__ w_r0,
    const float* __restrict__ w_l1, const float* __restrict__ w_r1,
    const float* __restrict__ w_l2, const float* __restrict__ w_r2,
    ushort_t* __restrict__ WT0, ushort_t* __restrict__ WT1,
    ushort_t* __restrict__ WT2, float* __restrict__ out) {
  const int blk = blockIdx.x, t = threadIdx.x;
  if (blk < 2048) {                        // norms + cast, wave per row
    int wid  = (blk * 256 + t) >> 6;
    int lane = t & 63;
    const float* row = x + (size_t)wid * FEAT;
    ushort_t* xr = xs + (size_t)wid * KD;
    float s = 0.f;
#pragma unroll
    for (int f0 = 0; f0 < FEAT; f0 += 64) {
      int f = f0 + lane;
      float v = row[f];
      s += v * v;
      xr[f] = f2bf_rne(v);
    }
#pragma unroll
    for (int off = 32; off > 0; off >>= 1) s += __shfl_down(s, off);
    if (lane == 0) sq[wid] = s;
    return;
  }
  int i = (blk - 2048) * 256 + t;          // 0 .. 753663
  if (i < NIMG * NCLS) out[i] = 0.f;
  if (i < 98304) {                         // WT0: 256 x 384
    int n = i / 384, k = i - n * 384;
    float v = (k < 192) ? w_l0[k * 256 + n] : w_r0[(k - 192) * 256 + n];
    WT0[i] = f2bf_rne(v);
  } else if (i < 98304 + 131072) {         // WT1: 256 x 512
    int j = i - 98304;
    int n = j / 512, k = j - n * 512;
    float v = (k < 256) ? w_l1[k * 256 + n] : w_r1[(k - 256) * 256 + n];
    WT1[j] = f2bf_rne(v);
  } else {                                 // WT2: 1024 x 512 (rows>=1000: 0)
    int j = i - (98304 + 131072);
    int n = j / 512, k = j - n * 512;
    float v = 0.f;
    if (n < NCLS)
      v = (k < 256) ? w_l2[k * NCLS + n] : w_r2[(k - 256) * NCLS + n];
    WT2[j] = f2bf_rne(v);
  }
}

// ---------------------------------------------------------------------------
// MFMA distance + top-9: 128 rows x 256 cols per block (two 128-col tiles
// folding into one tk). f32 keys, med3_f32 bubble. Grid 32 x 64.
__global__ __launch_bounds__(256, 4) void k_dist_topk(
    const ushort_t* __restrict__ xs, const float* __restrict__ sq,
    float* __restrict__ cand) {
  __shared__ __align__(16) char smem[24576];
  ushort_t* As = (ushort_t*)smem;            // [128][32] (granule-swizzled)
  ushort_t* Bs = (ushort_t*)(smem + 8192);
  float*    Ms = (float*)(smem + 19456);     // [128][10] merge buf

  const int t    = threadIdx.x;
  const int lane = t & 63;
  const int w    = t >> 6;
  const int l15  = lane & 15, lq = lane >> 4;
  const int rowStart = blockIdx.y * 128;
  const int colBase  = blockIdx.x * 256;
  const int mrow = (w >> 1) * 64;
  const int ncol = (w & 1) * 64;

  const int m0 = w * 128 + lane;
  const int r0 = m0 >> 2, r1 = r0 + 16;
  const int g0 = m0 & 3;
  const int gs0 = g0 ^ (r0 & 3);
  const int gs1 = g0 ^ (r1 & 3);
  const ushort_t* gA0 = xs + (size_t)(rowStart + r0) * KD + gs0 * 8;
  const ushort_t* gA1 = xs + (size_t)(rowStart + r1) * KD + gs1 * 8;
  ushort_t* lA = As + w * 1024;
  ushort_t* lB = Bs + w * 1024;

  const int pg = (lq ^ (l15 & 3)) * 8;
  int aoff[4], boff[4];
#pragma unroll
  for (int ti = 0; ti < 4; ++ti) aoff[ti] = (mrow + ti * 16 + l15) * 32 + pg;
#pragma unroll
  for (int tj = 0; tj < 4; ++tj) boff[tj] = (ncol + tj * 16 + l15) * 32 + pg;

  float tk[KNN];
#pragma unroll
  for (int n = 0; n < KNN; ++n) tk[n] = FINF;

  float* Ew = (float*)smem + w * (64 * 19);

#pragma unroll 1
  for (int ct = 0; ct < 2; ++ct) {
    const int colStart = colBase + ct * 128;
    const ushort_t* gB0 = xs + (size_t)(colStart + r0) * KD + gs0 * 8;
    const ushort_t* gB1 = xs + (size_t)(colStart + r1) * KD + gs1 * 8;

    f32x4 c00 = {}, c01 = {}, c02 = {}, c03 = {};
    f32x4 c10 = {}, c11 = {}, c12 = {}, c13 = {};
    f32x4 c20 = {}, c21 = {}, c22 = {}, c23 = {};
    f32x4 c30 = {}, c31 = {}, c32 = {}, c33 = {};

#pragma unroll 1
    for (int kt = 0; kt < 6; ++kt) {
      const int k0 = kt * 32;
      ASYNC16(gA0 + k0, lA);
      ASYNC16(gA1 + k0, lA + 512);
      ASYNC16(gB0 + k0, lB);
      ASYNC16(gB1 + k0, lB + 512);
      __syncthreads();
      bf16x8 a0 = *(const bf16x8*)(As + aoff[0]);
      bf16x8 a1 = *(const bf16x8*)(As + aoff[1]);
      bf16x8 a2 = *(const bf16x8*)(As + aoff[2]);
      bf16x8 a3 = *(const bf16x8*)(As + aoff[3]);
      bf16x8 b0 = *(const bf16x8*)(Bs + boff[0]);
      bf16x8 b1 = *(const bf16x8*)(Bs + boff[1]);
      bf16x8 b2 = *(const bf16x8*)(Bs + boff[2]);
      bf16x8 b3 = *(const bf16x8*)(Bs + boff[3]);
      c00 = MFMA(a0, b0, c00); c01 = MFMA(a0, b1, c01);
      c02 = MFMA(a0, b2, c02); c03 = MFMA(a0, b3, c03);
      c10 = MFMA(a1, b0, c10); c11 = MFMA(a1, b1, c11);
      c12 = MFMA(a1, b2, c12); c13 = MFMA(a1, b3, c13);
      c20 = MFMA(a2, b0, c20); c21 = MFMA(a2, b1, c21);
      c22 = MFMA(a2, b2, c22); c23 = MFMA(a2, b3, c23);
      c30 = MFMA(a3, b0, c30); c31 = MFMA(a3, b1, c31);
      c32 = MFMA(a3, b2, c32); c33 = MFMA(a3, b3, c33);
      __syncthreads();
    }

#define EPI_ROW(TI, CV)                                                      \
  do {                                                                       \
    f32x4 v_ = (CV);                                                         \
    Ew[((TI) * 16 + lq * 4 + 0) * 19 + l15] =                                \
        packf(fmaf(-2.0f, v_.x, sqv), mycol);                                \
    Ew[((TI) * 16 + lq * 4 + 1) * 19 + l15] =                                \
        packf(fmaf(-2.0f, v_.y, sqv), mycol);                                \
    Ew[((TI) * 16 + lq * 4 + 2) * 19 + l15] =                                \
        packf(fmaf(-2.0f, v_.z, sqv), mycol);                                \
    Ew[((TI) * 16 + lq * 4 + 3) * 19 + l15] =                                \
        packf(fmaf(-2.0f, v_.w, sqv), mycol);                                \
  } while (0)

#define EPI_TILE(TJ, C0, C1, C2, C3)                                         \
  do {                                                                       \
    int mycol = colStart + ncol + (TJ) * 16 + l15;                           \
    float sqv = sq[mycol];                                                   \
    EPI_ROW(0, C0); EPI_ROW(1, C1); EPI_ROW(2, C2); EPI_ROW(3, C3);          \
    _Pragma("unroll")                                                        \
    for (int c = 0; c < 16; ++c) bubble9f(tk, Ew[lane * 19 + c]);            \
  } while (0)

    EPI_TILE(0, c00, c10, c20, c30);
    EPI_TILE(1, c01, c11, c21, c31);
    EPI_TILE(2, c02, c12, c22, c32);
    EPI_TILE(3, c03, c13, c23, c33);

    __syncthreads();   // Ew (overlaps As/Bs) dead before next ct staging
  }

  // merge the two waves sharing each row half, write 9 keys per 256 cols
  if (w & 1) {
#pragma unroll
    for (int n = 0; n < KNN; ++n) Ms[(mrow + lane) * 10 + n] = tk[n];
  }
  __syncthreads();
  if (!(w & 1)) {
#pragma unroll
    for (int n = 0; n < KNN; ++n) bubble9f(tk, Ms[(mrow + lane) * 10 + n]);
    size_t base =
        (((size_t)(rowStart + mrow + lane)) * NCB + blockIdx.x) * KNN;
#pragma unroll
    for (int n = 0; n < KNN; ++n) cand[base + n] = tk[n];
  }
}

// ---------------------------------------------------------------------------
// fused: merge 32x9=288 f32 candidates -> 9 neighbor idx -> layer-0 gather.
__global__ __launch_bounds__(256) void k_reduce_gather(
    const float* __restrict__ cand, const float* __restrict__ x,
    int* __restrict__ idx, ushort_t* __restrict__ Ab0) {
  int wid  = (blockIdx.x * 256 + threadIdx.x) >> 6;
  int lane = threadIdx.x & 63;
  if (wid >= NN) return;
  const float* cv = cand + (size_t)wid * (NCB * KNN);
  float tk[KNN];
#pragma unroll
  for (int n = 0; n < KNN; ++n) tk[n] = FINF;
#pragma unroll
  for (int m = 0; m < 4; ++m) bubble9f(tk, cv[lane + 64 * m]);
  bubble9f(tk, (lane < 32) ? cv[lane + 256] : FINF);

  int nb[KNN];
  for (int r = 0; r < KNN; ++r) {
    float bm = tk[0];
#pragma unroll
    for (int off = 32; off > 0; off >>= 1)
      bm = fminf(bm, __shfl_xor(bm, off));
    if (tk[0] == bm) {                     // keys unique: exactly one lane
#pragma unroll
      for (int p = 0; p < KNN - 1; ++p) tk[p] = tk[p + 1];
      tk[KNN - 1] = FINF;
    }
    nb[r] = (int)(__float_as_uint(bm) & 0x1FFFu);
    if (lane == 0) idx[wid * KNN + r] = nb[r];
  }

#pragma unroll
  for (int f0 = 0; f0 < FEAT; f0 += 64) {
    int f = f0 + lane;
    float s = 0.f;
#pragma unroll
    for (int n = 0; n < KNN; ++n) s += x[(size_t)nb[n] * FEAT + f];
    Ab0[(size_t)wid * KL0 + f]        = f2bf_rne(s * (1.0f / KNN));
    Ab0[(size_t)wid * KL0 + FEAT + f] = f2bf_rne(x[(size_t)wid * FEAT + f]);
  }
}

// ---------------------------------------------------------------------------
// layer-1/2 agg build: 16B/lane, 2 rows per wave (32 lanes x 8 cols = 256).
__global__ __launch_bounds__(256) void k_gather_h(
    const ushort_t* __restrict__ hsrc, const int* __restrict__ idx,
    ushort_t* __restrict__ adst) {
  const int t = threadIdx.x;
  const int lane = t & 63, w = t >> 6;
  const int r  = (blockIdx.x * 4 + w) * 2 + (lane >> 5);
  const int cl = (lane & 31) * 8;
  int nb[KNN];
#pragma unroll
  for (int n = 0; n < KNN; ++n) nb[n] = idx[r * KNN + n];
  float s[8] = {};
#pragma unroll
  for (int n = 0; n < KNN; ++n) {
    uint4 v = *(const uint4*)(hsrc + (size_t)nb[n] * 512 + cl);
    s[0] += __uint_as_float(v.x << 16); s[1] += __uint_as_float(v.x & 0xFFFF0000u);
    s[2] += __uint_as_float(v.y << 16); s[3] += __uint_as_float(v.y & 0xFFFF0000u);
    s[4] += __uint_as_float(v.z << 16); s[5] += __uint_as_float(v.z & 0xFFFF0000u);
    s[6] += __uint_as_float(v.w << 16); s[7] += __uint_as_float(v.w & 0xFFFF0000u);
  }
  uint4 o;
  o.x = (uint_t)f2bf_rne(s[0] * (1.0f / KNN)) |
        ((uint_t)f2bf_rne(s[1] * (1.0f / KNN)) << 16);
  o.y = (uint_t)f2bf_rne(s[2] * (1.0f / KNN)) |
        ((uint_t)f2bf_rne(s[3] * (1.0f / KNN)) << 16);
  o.z = (uint_t)f2bf_rne(s[4] * (1.0f / KNN)) |
        ((uint_t)f2bf_rne(s[5] * (1.0f / KNN)) << 16);
  o.w = (uint_t)f2bf_rne(s[6] * (1.0f / KNN)) |
        ((uint_t)f2bf_rne(s[7] * (1.0f / KNN)) << 16);
  *(uint4*)(adst + (size_t)r * 512 + cl) = o;
}

// ---------------------------------------------------------------------------
// bf16 MFMA SAGE layer, BM=64 BN=64, N=256, 512 blocks, BK=64.
__global__ __launch_bounds__(256) void k_sage64(
    const ushort_t* __restrict__ Ab, const ushort_t* __restrict__ WT,
    const float* __restrict__ bias, ushort_t* __restrict__ hdst, int KT) {
  __shared__ __align__(16) char smem[16384];
  ushort_t* As = (ushort_t*)smem;            // 2 panels [64][32]
  ushort_t* Bs = (ushort_t*)(smem + 8192);
  const int blk = blockIdx.x;
  const int t = threadIdx.x;
  const int lane = t & 63, w = t >> 6;
  const int l15 = lane & 15, lq = lane >> 4;
  const int rowStart = (blk >> 2) * 64, colStart = (blk & 3) * 64;
  const int mrow = (w >> 1) * 32, ncol = (w & 1) * 32;

  const int rA = t >> 2, g = t & 3;
  const int gs = g ^ (rA & 3);
  const ushort_t* gA = Ab + (size_t)(rowStart + rA) * KT + gs * 8;
  const ushort_t* gB = WT + (size_t)(colStart + rA) * KT + gs * 8;
  ushort_t* lA = As + w * 512;
  ushort_t* lB = Bs + w * 512;

  const int pg = (lq ^ (l15 & 3)) * 8;
  const int aoff0 = (mrow + l15) * 32 + pg, aoff1 = (mrow + 16 + l15) * 32 + pg;
  const int boff0 = (ncol + l15) * 32 + pg, boff1 = (ncol + 16 + l15) * 32 + pg;

  f32x4 c00 = {}, c01 = {}, c10 = {}, c11 = {};
  const int nkt = KT >> 6;
#pragma unroll 1
  for (int kt = 0; kt < nkt; ++kt) {
    const int k0 = kt * 64;
    ASYNC16(gA + k0, lA);
    ASYNC16(gA + k0 + 32, lA + 2048);
    ASYNC16(gB + k0, lB);
    ASYNC16(gB + k0 + 32, lB + 2048);
    __syncthreads();
    bf16x8 a0 = *(const bf16x8*)(As + aoff0);
    bf16x8 a1 = *(const bf16x8*)(As + aoff1);
    bf16x8 b0 = *(const bf16x8*)(Bs + boff0);
    bf16x8 b1 = *(const bf16x8*)(Bs + boff1);
    c00 = MFMA(a0, b0, c00); c01 = MFMA(a0, b1, c01);
    c10 = MFMA(a1, b0, c10); c11 = MFMA(a1, b1, c11);
    bf16x8 a0p = *(const bf16x8*)(As + 2048 + aoff0);
    bf16x8 a1p = *(const bf16x8*)(As + 2048 + aoff1);
    bf16x8 b0p = *(const bf16x8*)(Bs + 2048 + boff0);
    bf16x8 b1p = *(const bf16x8*)(Bs + 2048 + boff1);
    c00 = MFMA(a0p, b0p, c00); c01 = MFMA(a0p, b1p, c01);
    c10 = MFMA(a1p, b0p, c10); c11 = MFMA(a1p, b1p, c11);
    __syncthreads();
  }

  const float bv0 = bias[colStart + ncol + l15];
  const float bv1 = bias[colStart + ncol + 16 + l15];
#define S64_ST(TI, TJ, CV, BV)                                               \
  do {                                                                       \
    f32x4 v_ = (CV);                                                         \
    int col_ = colStart + ncol + (TJ) * 16 + l15;                            \
    size_t rb_ = (size_t)(rowStart + mrow + (TI) * 16 + lq * 4);             \
    hdst[(rb_ + 0) * 512 + col_] = f2bf_rne(fmaxf(v_.x + (BV), 0.f));        \
    hdst[(rb_ + 1) * 512 + col_] = f2bf_rne(fmaxf(v_.y + (BV), 0.f));        \
    hdst[(rb_ + 2) * 512 + col_] = f2bf_rne(fmaxf(v_.z + (BV), 0.f));        \
    hdst[(rb_ + 3) * 512 + col_] = f2bf_rne(fmaxf(v_.w + (BV), 0.f));        \
  } while (0)
  S64_ST(0, 0, c00, bv0); S64_ST(0, 1, c01, bv1);
  S64_ST(1, 0, c10, bv0); S64_ST(1, 1, c11, bv1);
}

// ---------------------------------------------------------------------------
// bf16 MFMA layer-2 + fused global mean pool. BM=128 BN=128, N=1024 padded,
// KT=512, BK=64.
__global__ __launch_bounds__(256, 2) void k_sage128_pool(
    const ushort_t* __restrict__ Ab, const ushort_t* __restrict__ WT,
    const float* __restrict__ bias, float* __restrict__ out) {
  __shared__ __align__(16) char smem[32768];
  ushort_t* As = (ushort_t*)smem;            // 2 panels [128][32]
  ushort_t* Bs = (ushort_t*)(smem + 16384);
  __shared__ float Ps[2][128];

  const int t    = threadIdx.x;
  const int lane = t & 63;
  const int w    = t >> 6;
  const int l15  = lane & 15, lq = lane >> 4;
  const int rowStart = blockIdx.y * 128;
  const int colStart = blockIdx.x * 128;
  const int mrow = (w >> 1) * 64;
  const int ncol = (w & 1) * 64;
  const int KT = 512;

  const int rA0 = t >> 2, rA1 = rA0 + 64;
  const int g = t & 3;
  const int gsA0 = g ^ (rA0 & 3), gsA1 = g ^ (rA1 & 3);
  const ushort_t* gA0 = Ab + (size_t)(rowStart + rA0) * KT + gsA0 * 8;
  const ushort_t* gA1 = Ab + (size_t)(rowStart + rA1) * KT + gsA1 * 8;
  const ushort_t* gB0 = WT + (size_t)(colStart + rA0) * KT + gsA0 * 8;
  const ushort_t* gB1 = WT + (size_t)(colStart + rA1) * KT + gsA1 * 8;
  ushort_t* lA0 = As + w * 512;
  ushort_t* lA1 = As + 2048 + w * 512;
  ushort_t* lB0 = Bs + w * 512;
  ushort_t* lB1 = Bs + 2048 + w * 512;

  const int pg = (lq ^ (l15 & 3)) * 8;
  int aoff[4], boff[4];
#pragma unroll
  for (int ti = 0; ti < 4; ++ti) aoff[ti] = (mrow + ti * 16 + l15) * 32 + pg;
#pragma unroll
  for (int tj = 0; tj < 4; ++tj) boff[tj] = (ncol + tj * 16 + l15) * 32 + pg;

  f32x4 c00 = {}, c01 = {}, c02 = {}, c03 = {};
  f32x4 c10 = {}, c11 = {}, c12 = {}, c13 = {};
  f32x4 c20 = {}, c21 = {}, c22 = {}, c23 = {};
  f32x4 c30 = {}, c31 = {}, c32 = {}, c33 = {};

#define POOL_MFMA_PANEL(OFS)                                                 \
  do {                                                                       \
    bf16x8 a0 = *(const bf16x8*)(As + (OFS) + aoff[0]);                      \
    bf16x8 a1 = *(const bf16x8*)(As + (OFS) + aoff[1]);                      \
    bf16x8 a2 = *(const bf16x8*)(As + (OFS) + aoff[2]);                      \
    bf16x8 a3 = *(const bf16x8*)(As + (OFS) + aoff[3]);                      \
    bf16x8 b0v = *(const bf16x8*)(Bs + (OFS) + boff[0]);                     \
    bf16x8 b1v = *(const bf16x8*)(Bs + (OFS) + boff[1]);                     \
    bf16x8 b2v = *(const bf16x8*)(Bs + (OFS) + boff[2]);                     \
    bf16x8 b3v = *(const bf16x8*)(Bs + (OFS) + boff[3]);                     \
    c00 = MFMA(a0, b0v, c00); c01 = MFMA(a0, b1v, c01);                      \
    c02 = MFMA(a0, b2v, c02); c03 = MFMA(a0, b3v, c03);                      \
    c10 = MFMA(a1, b0v, c10); c11 = MFMA(a1, b1v, c11);                      \
    c12 = MFMA(a1, b2v, c12); c13 = MFMA(a1, b3v, c13);                      \
    c20 = MFMA(a2, b0v, c20); c21 = MFMA(a2, b1v, c21);                      \
    c22 = MFMA(a2, b2v, c22); c23 = MFMA(a2, b3v, c23);                      \
    c30 = MFMA(a3, b0v, c30); c31 = MFMA(a3, b1v, c31);                      \
    c32 = MFMA(a3, b2v, c32); c33 = MFMA(a3, b3v, c33);                      \
  } while (0)

#pragma unroll 1
  for (int kt = 0; kt < 8; ++kt) {
    const int k0 = kt * 64;
    ASYNC16(gA0 + k0, lA0);
    ASYNC16(gA1 + k0, lA1);
    ASYNC16(gA0 + k0 + 32, lA0 + 4096);
    ASYNC16(gA1 + k0 + 32, lA1 + 4096);
    ASYNC16(gB0 + k0, lB0);
    ASYNC16(gB1 + k0, lB1);
    ASYNC16(gB0 + k0 + 32, lB0 + 4096);
    ASYNC16(gB1 + k0 + 32, lB1 + 4096);
    __syncthreads();
    POOL_MFMA_PANEL(0);
    POOL_MFMA_PANEL(4096);
    __syncthreads();
  }

#define P_ACC(CV)                                                            \
  (fmaxf((CV).x + bv_, 0.f) + fmaxf((CV).y + bv_, 0.f) +                     \
   fmaxf((CV).z + bv_, 0.f) + fmaxf((CV).w + bv_, 0.f))

#define POOL_COL(TJ, C0, C1, C2, C3)                                         \
  do {                                                                       \
    int col_ = colStart + ncol + (TJ) * 16 + l15;                            \
    float bv_ = (col_ < NCLS) ? bias[col_] : 0.f;                            \
    float s_ = P_ACC(C0) + P_ACC(C1) + P_ACC(C2) + P_ACC(C3);                \
    s_ += __shfl_xor(s_, 16);                                                \
    s_ += __shfl_xor(s_, 32);                                                \
    if (lq == 0) Ps[w >> 1][ncol + (TJ) * 16 + l15] = s_;                    \
  } while (0)

  POOL_COL(0, c00, c10, c20, c30);
  POOL_COL(1, c01, c11, c21, c31);
  POOL_COL(2, c02, c12, c22, c32);
  POOL_COL(3, c03, c13, c23, c33);

  __syncthreads();
  if (t < 128) {
    int col = colStart + t;
    if (col < NCLS) {
      float s = Ps[0][t] + Ps[1][t];
      int img = rowStart / NPP;
      atomicAdd(out + (size_t)img * NCLS + col, s * (1.0f / NPP));
    }
  }
}

// ---------------------------------------------------------------------------
extern "C" void kernel_launch(void* const* d_in, const int* in_sizes, int n_in,
                              void* d_out, int out_size, void* d_ws,
                              size_t ws_size, hipStream_t stream) {
  const float* x    = (const float*)d_in[0];
  const float* w_l0 = (const float*)d_in[1];
  const float* b_l0 = (const float*)d_in[2];
  const float* w_r0 = (const float*)d_in[3];
  const float* w_l1 = (const float*)d_in[4];
  const float* b_l1 = (const float*)d_in[5];
  const float* w_r1 = (const float*)d_in[6];
  const float* w_l2 = (const float*)d_in[7];
  const float* b_l2 = (const float*)d_in[8];
  const float* w_r2 = (const float*)d_in[9];
  float* out = (float*)d_out;

  char* ws = (char*)d_ws;
  // WT lifetime rule (R9 lesson): WTs written by k_prep live OUTSIDE the
  // cand region; only Ab1/Ab2 (written after k_reduce_gather) overlap it.
  // sq [0,32K) | idx [32K,320K) | cand [327680, 9764864) |
  // xs [19202048, 22347776) | Ab0 [22347776, 28639232) |
  // WT0 @28639232 WT1 @28835840 WT2 @29097984..30146560 |
  // Ab1 [327680, 8716288) Ab2 [8716288, 17104896)
  float*    sq   = (float*)(ws);
  int*      idx  = (int*)(ws + 32768);
  float*    cand = (float*)(ws + 327680);
  ushort_t* xs   = (ushort_t*)(ws + 19202048);
  ushort_t* Ab0  = (ushort_t*)(ws + 22347776);
  ushort_t* WT0  = (ushort_t*)(ws + 28639232);
  ushort_t* WT1  = (ushort_t*)(ws + 28835840);
  ushort_t* WT2  = (ushort_t*)(ws + 29097984);
  ushort_t* Ab1  = (ushort_t*)(ws + 327680);
  ushort_t* Ab2  = (ushort_t*)(ws + 8716288);

  k_prep<<<4992, 256, 0, stream>>>(x, sq, xs, w_l0, w_r0, w_l1, w_r1,
                                   w_l2, w_r2, WT0, WT1, WT2, out);
  k_dist_topk<<<dim3(NCB, 64), 256, 0, stream>>>(xs, sq, cand);
  k_reduce_gather<<<2048, 256, 0, stream>>>(cand, x, idx, Ab0);
  k_sage64<<<512, 256, 0, stream>>>(Ab0, WT0, b_l0, Ab1 + 256, KL0);
  k_gather_h<<<1024, 256, 0, stream>>>(Ab1 + 256, idx, Ab1);
  k_sage64<<<512, 256, 0, stream>>>(Ab1, WT1, b_l1, Ab2 + 256, 512);
  k_gather_h<<<1024, 256, 0, stream>>>(Ab2 + 256, idx, Ab2);
  k_sage128_pool<<<dim3(8, 64), 256, 0, stream>>>(Ab2, WT2, b_l2, out);
}